// Round 10
// baseline (107.865 us; speedup 1.0000x reference)
//
#include <hip/hip_runtime.h>

typedef short   bf16x8 __attribute__((ext_vector_type(8)));
typedef float   f32x4  __attribute__((ext_vector_type(4)));

#define NVEC   131072      // 32*64*64 vectors
#define HW     4096
#define CHW    262144
#define QOFF   1
#define PERPOFF 8388609
#define ENCOFF  8388610

// ws layout: counts[512] @0, double loss @2048, float bias[512] @4096,
//            ushort wbf[512*64] @8192 (64 KB), int idx[131072] @73728

__device__ inline unsigned short f2bf(float f) {   // RTNE float->bf16
    unsigned int u = __float_as_uint(f);
    u += 0x7fffu + ((u >> 16) & 1u);
    return (unsigned short)(u >> 16);
}

// per code: bf16 copy of W + bias = -0.5*||w||^2 (f32-exact).
// Block 0 additionally zeroes counts + loss.
__global__ __launch_bounds__(64) void vq_prep(const float* __restrict__ wt,
                                              float* __restrict__ bias,
                                              unsigned short* __restrict__ wbf,
                                              int* __restrict__ counts,
                                              double* __restrict__ loss) {
    int c = blockIdx.x, d = threadIdx.x;
    if (c == 0) {
#pragma unroll
        for (int i = 0; i < 8; ++i) counts[d * 8 + i] = 0;
        if (d == 0) loss[0] = 0.0;
    }
    float v = wt[c * 64 + d];
    wbf[c * 64 + d] = f2bf(v);
    float s = v * v;
    for (int off = 32; off; off >>= 1) s += __shfl_down(s, off, 64);
    if (d == 0) bias[c] = -0.5f * s;
}

// 512 blocks x 512 threads (8 waves), 2 blocks/CU (VGPR capped at 128).
// Wave handles 32 rows: 2 row-sets of 16.
// Scores via mfma_f32_16x16x32_bf16 with C preloaded = -wsq/2; argmax.
__global__ __launch_bounds__(512, 4) void vq_assign(
    const float* __restrict__ x, const float* __restrict__ wt,
    const float* __restrict__ bias, const unsigned short* __restrict__ wbf,
    float* __restrict__ out, int* __restrict__ idx,
    int* __restrict__ counts, double* __restrict__ loss_acc)
{
    __shared__ unsigned short wl[512 * 64];   // 64 KB, XOR-swizzled rows
    __shared__ float  biasl[512];
    __shared__ int    hc[512];
    __shared__ int    winners[256];
    __shared__ double lred[8];

    const int t = threadIdx.x, b = blockIdx.x;
    const int batch  = b >> 4;
    const int posblk = (b & 15) << 8;

    // ---- stage W bf16 into LDS with st-swizzle (row c: byte ^= (c&7)<<4) ----
    {
        const ulonglong2* src = (const ulonglong2*)wbf;   // 16B units
#pragma unroll
        for (int i = 0; i < 8; ++i) {
            int u  = t + 512 * i;          // 16B-unit index, 0..4095
            int c  = u >> 3;               // code row
            int bo = (u & 7) << 4;         // byte-in-row
            ulonglong2 v = src[u];
            *(ulonglong2*)((char*)wl + ((c << 7) | (bo ^ ((c & 7) << 4)))) = v;
        }
        biasl[t] = bias[t];
        hc[t] = 0;
    }
    __syncthreads();

    const int wv = t >> 6, l = t & 63;
    const int g  = l >> 4, cl = l & 15;
    const int posw = posblk + (wv << 5);      // this wave's 32 pos
    const int d0 = g << 3;

    // ---- load X f32 directly in A-fragment layout ----
    float xs[2][16];
    const float* xb = x + (size_t)batch * CHW + posw + cl;
#pragma unroll
    for (int s = 0; s < 2; ++s)
#pragma unroll
        for (int j = 0; j < 8; ++j) {
            xs[s][j]     = xb[(size_t)(d0 + j) * HW + 16 * s];
            xs[s][j + 8] = xb[(size_t)(32 + d0 + j) * HW + 16 * s];
        }

    bf16x8 af[2][2];
#pragma unroll
    for (int s = 0; s < 2; ++s)
#pragma unroll
        for (int h = 0; h < 2; ++h)
#pragma unroll
            for (int i = 0; i < 8; ++i)
                af[s][h][i] = (short)f2bf(xs[s][8 * h + i]);

    // ---- score loop: 32 col-tiles of 16 codes ----
    float best[2][4]; int bidx[2][4];
#pragma unroll
    for (int s = 0; s < 2; ++s)
#pragma unroll
        for (int i = 0; i < 4; ++i) { best[s][i] = -1e30f; bidx[s][i] = 0; }

    const char* wlb = (const char*)wl;
#pragma unroll 4
    for (int tt = 0; tt < 32; ++tt) {
        int c  = (tt << 4) + cl;
        int rb = c << 7;
        int sw = (c & 7) << 4;
        bf16x8 b0 = *(const bf16x8*)(wlb + (rb | ((16 * g) ^ sw)));
        bf16x8 b1 = *(const bf16x8*)(wlb + (rb | ((64 + 16 * g) ^ sw)));
        float bs = biasl[c];
#pragma unroll
        for (int s = 0; s < 2; ++s) {
            f32x4 acc = {bs, bs, bs, bs};
            acc = __builtin_amdgcn_mfma_f32_16x16x32_bf16(af[s][0], b0, acc, 0, 0, 0);
            acc = __builtin_amdgcn_mfma_f32_16x16x32_bf16(af[s][1], b1, acc, 0, 0, 0);
#pragma unroll
            for (int i = 0; i < 4; ++i)
                if (acc[i] > best[s][i]) { best[s][i] = acc[i]; bidx[s][i] = c; }
        }
    }

    // ---- 16-lane butterfly argmax (tie -> smaller index) ----
#pragma unroll
    for (int s = 0; s < 2; ++s)
#pragma unroll
        for (int i = 0; i < 4; ++i) {
            float bd = best[s][i]; int bi = bidx[s][i];
#pragma unroll
            for (int off = 1; off < 16; off <<= 1) {
                float od = __shfl_xor(bd, off, 64);
                int   oi = __shfl_xor(bi, off, 64);
                if (od > bd || (od == bd && oi < bi)) { bd = od; bi = oi; }
            }
            bidx[s][i] = bi;
        }

    // winners to LDS (row-in-wave = 16s + 4g + i), + histogram
    if (cl == 0) {
#pragma unroll
        for (int s = 0; s < 2; ++s)
#pragma unroll
            for (int i = 0; i < 4; ++i) {
                int w = bidx[s][i];
                winners[(wv << 5) + (s << 4) + (g << 2) + i] = w;
                atomicAdd(&hc[w], 1);
            }
    }
    __syncthreads();

    // ---- epilogue: quantized_st + loss (f32-exact) ----
    float* outb = out + QOFF + (size_t)batch * CHW + posw + cl;
    float ls = 0.f;
#pragma unroll
    for (int s = 0; s < 2; ++s) {
        int widx = winners[(wv << 5) + (s << 4) + cl];
        float q[16];
        *(float4*)&q[0]  = *(const float4*)(wt + widx * 64 + d0);
        *(float4*)&q[4]  = *(const float4*)(wt + widx * 64 + d0 + 4);
        *(float4*)&q[8]  = *(const float4*)(wt + widx * 64 + 32 + d0);
        *(float4*)&q[12] = *(const float4*)(wt + widx * 64 + 32 + d0 + 4);
#pragma unroll
        for (int j = 0; j < 8; ++j) {
            float da = q[j]     - xs[s][j];
            float db = q[j + 8] - xs[s][j + 8];
            ls += da * da + db * db;
            outb[(size_t)(d0 + j) * HW + 16 * s]      = xs[s][j]     + da;
            outb[(size_t)(32 + d0 + j) * HW + 16 * s] = xs[s][j + 8] + db;
        }
    }

    // compact index write (enc kernel expands it)
    if (t < 256)
        idx[(size_t)batch * 4096 + posblk + t] = winners[t];

    // ---- loss reduction ----
    double lsd = (double)ls;
    for (int off = 32; off; off >>= 1) lsd += __shfl_down(lsd, off, 64);
    if (l == 0) lred[wv] = lsd;
    __syncthreads();
    if (t == 0) {
        double s = 0.0;
#pragma unroll
        for (int i = 0; i < 8; ++i) s += lred[i];
        atomicAdd(loss_acc, s);
    }

    int v0 = hc[t];
    if (v0) atomicAdd(&counts[t], v0);
}

// One-hot expansion as a flat float4 NT stream (16B/lane), 2048 blocks.
// Region [enc+2, enc+2+4*16777215) is 16B-aligned; head/tail scalar.
// Block 0 also computes loss/perplexity (counts+loss complete at launch).
__global__ __launch_bounds__(256) void vq_enc(const int* __restrict__ idx,
                                              float* __restrict__ enc,
                                              const int* __restrict__ counts,
                                              const double* __restrict__ loss_acc,
                                              float* __restrict__ out) {
    const int t = threadIdx.x, b = blockIdx.x;
    if (b == 0) {
        __shared__ double red[256];
        double p0 = (double)counts[t]       * (1.0 / 131072.0);
        double p1 = (double)counts[t + 256] * (1.0 / 131072.0);
        red[t] = p0 * log(p0 + 1e-10) + p1 * log(p1 + 1e-10);
        __syncthreads();
        for (int s = 128; s; s >>= 1) {
            if (t < s) red[t] += red[t + s];
            __syncthreads();
        }
        if (t == 0) {
            out[PERPOFF] = (float)exp(-red[0]);
            out[0] = (float)(loss_acc[0] * 1.25 / 8388608.0);
            int id0 = idx[0], idL = idx[131071];
            enc[0] = (id0 == 0) ? 1.f : 0.f;
            enc[1] = (id0 == 1) ? 1.f : 0.f;
            enc[67108862] = (idL == 510) ? 1.f : 0.f;
            enc[67108863] = (idL == 511) ? 1.f : 0.f;
        }
    }

    const unsigned gid = (unsigned)b * 256u + (unsigned)t;
#pragma unroll 4
    for (int i = 0; i < 32; ++i) {
        unsigned un = (unsigned)i * 524288u + gid;     // float4 unit index
        if (un >= 16777215u) break;                    // only last thread's last iter
        unsigned e0   = 2u + 4u * un;                  // first f32 element
        unsigned row0 = e0 >> 9;
        unsigned row3 = (e0 + 3u) >> 9;
        int id0 = idx[row0];
        int id3 = idx[row3];
        f32x4 v;
#pragma unroll
        for (int k = 0; k < 4; ++k) {
            unsigned p   = e0 + (unsigned)k;
            int      idk = ((p >> 9) == row0) ? id0 : id3;
            v[k] = ((int)(p & 511u) == idk) ? 1.f : 0.f;
        }
        __builtin_nontemporal_store(v, (f32x4*)(enc + e0));
    }
}

extern "C" void kernel_launch(void* const* d_in, const int* in_sizes, int n_in,
                              void* d_out, int out_size, void* d_ws, size_t ws_size,
                              hipStream_t stream) {
    const float* x  = (const float*)d_in[0];
    const float* wt = (const float*)d_in[1];
    float* out = (float*)d_out;
    char* ws = (char*)d_ws;

    int*            counts = (int*)ws;
    double*         loss   = (double*)(ws + 2048);
    float*          bias   = (float*)(ws + 4096);
    unsigned short* wbf    = (unsigned short*)(ws + 8192);
    int*            idx    = (int*)(ws + 73728);
    float*          enc    = out + ENCOFF;

    vq_prep<<<512, 64, 0, stream>>>(wt, bias, wbf, counts, loss);
    vq_assign<<<512, 512, 0, stream>>>(x, wt, bias, wbf, out, idx, counts, loss);
    vq_enc<<<2048, 256, 0, stream>>>(idx, enc, counts, loss, out);
}

// Round 11
// 98.067 us; speedup vs baseline: 1.0999x; 1.0999x over previous
//
#include <hip/hip_runtime.h>

typedef short   bf16x8 __attribute__((ext_vector_type(8)));
typedef float   f32x4  __attribute__((ext_vector_type(4)));
typedef float   f32x2  __attribute__((ext_vector_type(2)));

#define NVEC   131072      // 32*64*64 vectors
#define HW     4096
#define CHW    262144
#define QOFF   1
#define PERPOFF 8388609
#define ENCOFF  8388610

// ws layout:
//   0      : int counts_p[32][512]  (65536 B)  32-way-spread histogram partials
//   65536  : double loss_acc        (8 B)
//   65600  : float bias[512]        (2048 B)
//   67712  : ushort wbf[512*64]     (65536 B, 16B-aligned)
//   133248 : int idx[131072]        (524288 B)

__device__ inline unsigned short f2bf(float f) {   // RTNE float->bf16
    unsigned int u = __float_as_uint(f);
    u += 0x7fffu + ((u >> 16) & 1u);
    return (unsigned short)(u >> 16);
}

// per code: bf16 copy of W + bias = -0.5*||w||^2 (f32-exact).
// Blocks 0..31 zero the 32 histogram partials; block 0 zeroes loss.
__global__ __launch_bounds__(64) void vq_prep(const float* __restrict__ wt,
                                              float* __restrict__ bias,
                                              unsigned short* __restrict__ wbf,
                                              int* __restrict__ counts_p,
                                              double* __restrict__ loss) {
    int c = blockIdx.x, d = threadIdx.x;
    if (c < 32) {
#pragma unroll
        for (int i = 0; i < 8; ++i) counts_p[(c << 9) + (d << 3) + i] = 0;
        if (c == 0 && d == 0) loss[0] = 0.0;
    }
    float v = wt[c * 64 + d];
    wbf[c * 64 + d] = f2bf(v);
    float s = v * v;
    for (int off = 32; off; off >>= 1) s += __shfl_down(s, off, 64);
    if (d == 0) bias[c] = -0.5f * s;
}

// 512 blocks x 512 threads (8 waves), no VGPR cap (R6 best-known config).
// Wave handles 32 rows: 2 row-sets of 16.
// Scores via mfma_f32_16x16x32_bf16 with C preloaded = -wsq/2; argmax.
__global__ __launch_bounds__(512) void vq_assign(
    const float* __restrict__ x, const float* __restrict__ wt,
    const float* __restrict__ bias, const unsigned short* __restrict__ wbf,
    float* __restrict__ out, int* __restrict__ idx,
    int* __restrict__ counts_p, double* __restrict__ loss_acc)
{
    __shared__ unsigned short wl[512 * 64];   // 64 KB, XOR-swizzled rows
    __shared__ float  biasl[512];
    __shared__ int    hc[512];
    __shared__ int    winners[256];
    __shared__ double lred[8];

    const int t = threadIdx.x, b = blockIdx.x;
    const int batch  = b >> 4;
    const int posblk = (b & 15) << 8;

    // ---- stage W bf16 into LDS with st-swizzle (row c: byte ^= (c&7)<<4) ----
    {
        const ulonglong2* src = (const ulonglong2*)wbf;   // 16B units
#pragma unroll
        for (int i = 0; i < 8; ++i) {
            int u  = t + 512 * i;          // 16B-unit index, 0..4095
            int c  = u >> 3;               // code row
            int bo = (u & 7) << 4;         // byte-in-row
            ulonglong2 v = src[u];
            *(ulonglong2*)((char*)wl + ((c << 7) | (bo ^ ((c & 7) << 4)))) = v;
        }
        biasl[t] = bias[t];
        hc[t] = 0;
    }
    __syncthreads();

    const int wv = t >> 6, l = t & 63;
    const int g  = l >> 4, cl = l & 15;
    const int posw = posblk + (wv << 5);      // this wave's 32 pos
    const int d0 = g << 3;

    // ---- load X f32 directly in A-fragment layout ----
    float xs[2][16];
    const float* xb = x + (size_t)batch * CHW + posw + cl;
#pragma unroll
    for (int s = 0; s < 2; ++s)
#pragma unroll
        for (int j = 0; j < 8; ++j) {
            xs[s][j]     = xb[(size_t)(d0 + j) * HW + 16 * s];
            xs[s][j + 8] = xb[(size_t)(32 + d0 + j) * HW + 16 * s];
        }

    bf16x8 af[2][2];
#pragma unroll
    for (int s = 0; s < 2; ++s)
#pragma unroll
        for (int h = 0; h < 2; ++h)
#pragma unroll
            for (int i = 0; i < 8; ++i)
                af[s][h][i] = (short)f2bf(xs[s][8 * h + i]);

    // ---- score loop: 32 col-tiles of 16 codes ----
    float best[2][4]; int bidx[2][4];
#pragma unroll
    for (int s = 0; s < 2; ++s)
#pragma unroll
        for (int i = 0; i < 4; ++i) { best[s][i] = -1e30f; bidx[s][i] = 0; }

    const char* wlb = (const char*)wl;
#pragma unroll 4
    for (int tt = 0; tt < 32; ++tt) {
        int c  = (tt << 4) + cl;
        int rb = c << 7;
        int sw = (c & 7) << 4;
        bf16x8 b0 = *(const bf16x8*)(wlb + (rb | ((16 * g) ^ sw)));
        bf16x8 b1 = *(const bf16x8*)(wlb + (rb | ((64 + 16 * g) ^ sw)));
        float bs = biasl[c];
#pragma unroll
        for (int s = 0; s < 2; ++s) {
            f32x4 acc = {bs, bs, bs, bs};
            acc = __builtin_amdgcn_mfma_f32_16x16x32_bf16(af[s][0], b0, acc, 0, 0, 0);
            acc = __builtin_amdgcn_mfma_f32_16x16x32_bf16(af[s][1], b1, acc, 0, 0, 0);
#pragma unroll
            for (int i = 0; i < 4; ++i)
                if (acc[i] > best[s][i]) { best[s][i] = acc[i]; bidx[s][i] = c; }
        }
    }

    // ---- 16-lane butterfly argmax (tie -> smaller index) ----
#pragma unroll
    for (int s = 0; s < 2; ++s)
#pragma unroll
        for (int i = 0; i < 4; ++i) {
            float bd = best[s][i]; int bi = bidx[s][i];
#pragma unroll
            for (int off = 1; off < 16; off <<= 1) {
                float od = __shfl_xor(bd, off, 64);
                int   oi = __shfl_xor(bi, off, 64);
                if (od > bd || (od == bd && oi < bi)) { bd = od; bi = oi; }
            }
            bidx[s][i] = bi;
        }

    // winners to LDS (row-in-wave = 16s + 4g + i), + histogram
    if (cl == 0) {
#pragma unroll
        for (int s = 0; s < 2; ++s)
#pragma unroll
            for (int i = 0; i < 4; ++i) {
                int w = bidx[s][i];
                winners[(wv << 5) + (s << 4) + (g << 2) + i] = w;
                atomicAdd(&hc[w], 1);
            }
    }
    __syncthreads();

    // ---- epilogue: quantized_st + loss (f32-exact) ----
    float* outb = out + QOFF + (size_t)batch * CHW + posw + cl;
    float ls = 0.f;
#pragma unroll
    for (int s = 0; s < 2; ++s) {
        int widx = winners[(wv << 5) + (s << 4) + cl];
        float q[16];
        *(float4*)&q[0]  = *(const float4*)(wt + widx * 64 + d0);
        *(float4*)&q[4]  = *(const float4*)(wt + widx * 64 + d0 + 4);
        *(float4*)&q[8]  = *(const float4*)(wt + widx * 64 + 32 + d0);
        *(float4*)&q[12] = *(const float4*)(wt + widx * 64 + 32 + d0 + 4);
#pragma unroll
        for (int j = 0; j < 8; ++j) {
            float da = q[j]     - xs[s][j];
            float db = q[j + 8] - xs[s][j + 8];
            ls += da * da + db * db;
            outb[(size_t)(d0 + j) * HW + 16 * s]      = xs[s][j]     + da;
            outb[(size_t)(32 + d0 + j) * HW + 16 * s] = xs[s][j + 8] + db;
        }
    }

    // compact index write (enc kernel expands it)
    if (t < 256)
        idx[(size_t)batch * 4096 + posblk + t] = winners[t];

    // ---- loss reduction ----
    double lsd = (double)ls;
    for (int off = 32; off; off >>= 1) lsd += __shfl_down(lsd, off, 64);
    if (l == 0) lred[wv] = lsd;
    __syncthreads();
    if (t == 0) {
        double s = 0.0;
#pragma unroll
        for (int i = 0; i < 8; ++i) s += lred[i];
        atomicAdd(loss_acc, s);
    }

    // histogram flush into 32-way-spread partials (16x less line contention)
    int v0 = hc[t];
    if (v0) atomicAdd(&counts_p[((b & 31) << 9) + t], v0);
}

// One-hot expansion: each line written exactly once, nontemporal (proven ~39us).
__global__ __launch_bounds__(256) void vq_enc(const int* __restrict__ idx,
                                              f32x2* __restrict__ enc) {
    int gid = blockIdx.x * 256 + threadIdx.x;   // 33,554,432 threads
    int row = gid >> 8;                          // 256 f32x2 per row
    int pos = (gid & 255) << 1;
    int id = idx[row];
    f32x2 v;
    v.x = (id == pos)     ? 1.f : 0.f;
    v.y = (id == pos + 1) ? 1.f : 0.f;
    __builtin_nontemporal_store(v, &enc[gid]);
}

__global__ __launch_bounds__(512) void vq_fin(const int* __restrict__ counts_p,
                                              const double* __restrict__ loss_acc,
                                              float* __restrict__ out) {
    __shared__ double red[512];
    int t = threadIdx.x;
    int cnt = 0;
#pragma unroll
    for (int k = 0; k < 32; ++k) cnt += counts_p[(k << 9) + t];
    double p = (double)cnt * (1.0 / 131072.0);
    red[t] = p * log(p + 1e-10);
    __syncthreads();
    for (int s = 256; s; s >>= 1) {
        if (t < s) red[t] += red[t + s];
        __syncthreads();
    }
    if (t == 0) {
        out[PERPOFF] = (float)exp(-red[0]);
        out[0] = (float)(loss_acc[0] * 1.25 / 8388608.0);
    }
}

extern "C" void kernel_launch(void* const* d_in, const int* in_sizes, int n_in,
                              void* d_out, int out_size, void* d_ws, size_t ws_size,
                              hipStream_t stream) {
    const float* x  = (const float*)d_in[0];
    const float* wt = (const float*)d_in[1];
    float* out = (float*)d_out;
    char* ws = (char*)d_ws;

    int*            counts_p = (int*)ws;
    double*         loss     = (double*)(ws + 65536);
    float*          bias     = (float*)(ws + 65600);
    unsigned short* wbf      = (unsigned short*)(ws + 67712);
    int*            idx      = (int*)(ws + 133248);
    float*          enc      = out + ENCOFF;

    vq_prep<<<512, 64, 0, stream>>>(wt, bias, wbf, counts_p, loss);
    vq_assign<<<512, 512, 0, stream>>>(x, wt, bias, wbf, out, idx, counts_p, loss);
    vq_enc<<<131072, 256, 0, stream>>>(idx, (f32x2*)enc);
    vq_fin<<<1, 512, 0, stream>>>(counts_p, loss, out);
}